// Round 1
// baseline (1000.690 us; speedup 1.0000x reference)
//
#include <hip/hip_runtime.h>
#include <hip/hip_bf16.h>
#include <cstdint>
#include <math.h>

#define S_TOT 16384
#define V_VOC 2048
#define B_B   32
#define T_T   64
#define L_L   16
#define PLANE 1024

// workspace layout (bytes)
static const size_t OFF_ET  = 0;                   // Et bf16 [V][S]: 2048*16384*2 = 67108864
static const size_t OFF_EM  = 67108864;            // em f32 [B*T][S]: 33554432*4 = 134217728
static const size_t OFF_LSE = OFF_EM + 134217728;  // row_lse f32 [S]
static const size_t OFF_TT  = OFF_LSE + 65536;     // Tt bf16 [7][S]

__device__ __forceinline__ unsigned short f2bf(float f) {
  unsigned int u = __float_as_uint(f);
  u = (u + 0x7fffu + ((u >> 16) & 1u)) >> 16;   // round-to-nearest-even
  return (unsigned short)u;
}
__device__ __forceinline__ float bflo(unsigned int w) { return __uint_as_float(w << 16); }
__device__ __forceinline__ float bfhi(unsigned int w) { return __uint_as_float(w & 0xffff0000u); }

// ---------------- K1: per-state logsumexp over vocab ----------------
__global__ void k_row_lse(const float* __restrict__ W, float* __restrict__ lse) {
  const int row = blockIdx.x;
  const int tid = threadIdx.x;          // 128 threads, 2 waves
  const float4* rp = (const float4*)(W + (size_t)row * V_VOC);
  float v[16];
#pragma unroll
  for (int j = 0; j < 4; ++j) {
    float4 q = rp[tid + j * 128];
    v[4*j+0] = q.x; v[4*j+1] = q.y; v[4*j+2] = q.z; v[4*j+3] = q.w;
  }
  float m = v[0];
#pragma unroll
  for (int j = 1; j < 16; ++j) m = fmaxf(m, v[j]);
#pragma unroll
  for (int o = 32; o >= 1; o >>= 1) m = fmaxf(m, __shfl_xor(m, o));
  __shared__ float sm[2];
  __shared__ float ss[2];
  const int wid = tid >> 6;
  if ((tid & 63) == 0) sm[wid] = m;
  __syncthreads();
  m = fmaxf(sm[0], sm[1]);
  float s = 0.f;
#pragma unroll
  for (int j = 0; j < 16; ++j) s += expf(v[j] - m);
#pragma unroll
  for (int o = 32; o >= 1; o >>= 1) s += __shfl_xor(s, o);
  if ((tid & 63) == 0) ss[wid] = s;
  __syncthreads();
  if (tid == 0) lse[row] = m + logf(ss[0] + ss[1]);
}

// ---------------- K2: transpose W (S,V) f32 -> Et (V,S) bf16 ----------------
__global__ void k_transpose(const float* __restrict__ W, unsigned short* __restrict__ Et) {
  __shared__ float t[64][33];           // [s][v], padded
  const int s0 = blockIdx.x * 64;
  const int v0 = blockIdx.y * 32;
  const int tid = threadIdx.x;          // 256
  const int r = tid >> 3, c = (tid & 7) * 4;
#pragma unroll
  for (int it = 0; it < 2; ++it) {
    const float* src = W + (size_t)(s0 + r + it * 32) * V_VOC + v0 + c;
    float4 q = *(const float4*)src;
    t[r + it * 32][c + 0] = q.x; t[r + it * 32][c + 1] = q.y;
    t[r + it * 32][c + 2] = q.z; t[r + it * 32][c + 3] = q.w;
  }
  __syncthreads();
  const int vv = tid >> 3, cs = (tid & 7) * 8;
  unsigned int w0 = (unsigned int)f2bf(t[cs + 0][vv]) | ((unsigned int)f2bf(t[cs + 1][vv]) << 16);
  unsigned int w1 = (unsigned int)f2bf(t[cs + 2][vv]) | ((unsigned int)f2bf(t[cs + 3][vv]) << 16);
  unsigned int w2 = (unsigned int)f2bf(t[cs + 4][vv]) | ((unsigned int)f2bf(t[cs + 5][vv]) << 16);
  unsigned int w3 = (unsigned int)f2bf(t[cs + 6][vv]) | ((unsigned int)f2bf(t[cs + 7][vv]) << 16);
  uint4 out = make_uint4(w0, w1, w2, w3);
  *(uint4*)(Et + (size_t)(v0 + vv) * S_TOT + s0 + cs) = out;
}

// ---------------- K3: transition softmax -> probabilities, (7,S) bf16 ----------------
__global__ void k_tsoftmax(const float* __restrict__ tw, unsigned short* __restrict__ Tt) {
  const int s = blockIdx.x * 256 + threadIdx.x;
  float x[7];
#pragma unroll
  for (int k = 0; k < 7; ++k) x[k] = tw[(size_t)s * 7 + k];
  float m = x[0];
#pragma unroll
  for (int k = 1; k < 7; ++k) m = fmaxf(m, x[k]);
  float e[7]; float sum = 0.f;
#pragma unroll
  for (int k = 0; k < 7; ++k) { e[k] = expf(x[k] - m); sum += e[k]; }
  const float inv = 1.f / sum;
#pragma unroll
  for (int k = 0; k < 7; ++k) Tt[(size_t)k * S_TOT + s] = f2bf(e[k] * inv);
}

// ---------------- K4: em[bt,s] = sum_l Et[tok_l][s] - L*lse[s] ----------------
__global__ void k_em(const unsigned short* __restrict__ Et, const int* __restrict__ stories,
                     const float* __restrict__ lse, float* __restrict__ em) {
  const int bt = blockIdx.y;
  __shared__ int toks[L_L];
  if (threadIdx.x < L_L) toks[threadIdx.x] = stories[bt * L_L + threadIdx.x];
  __syncthreads();
  const int s = blockIdx.x * 2048 + threadIdx.x * 8;
  float acc[8] = {0.f, 0.f, 0.f, 0.f, 0.f, 0.f, 0.f, 0.f};
#pragma unroll
  for (int l = 0; l < L_L; ++l) {
    const uint4* p = (const uint4*)(Et + ((size_t)toks[l] << 14) + s);
    uint4 q = *p;
    acc[0] += bflo(q.x); acc[1] += bfhi(q.x);
    acc[2] += bflo(q.y); acc[3] += bfhi(q.y);
    acc[4] += bflo(q.z); acc[5] += bfhi(q.z);
    acc[6] += bflo(q.w); acc[7] += bfhi(q.w);
  }
  const float4* lp = (const float4*)(lse + s);
  float4 l0 = lp[0], l1 = lp[1];
  float4 o0, o1;
  o0.x = acc[0] - 16.f * l0.x; o0.y = acc[1] - 16.f * l0.y;
  o0.z = acc[2] - 16.f * l0.z; o0.w = acc[3] - 16.f * l0.w;
  o1.x = acc[4] - 16.f * l1.x; o1.y = acc[5] - 16.f * l1.y;
  o1.z = acc[6] - 16.f * l1.z; o1.w = acc[7] - 16.f * l1.w;
  float4* op = (float4*)(em + (size_t)bt * S_TOT + s);
  op[0] = o0; op[1] = o1;
}

// ---------------- K5: scaled forward recursion, one block per batch ----------------
__device__ __forceinline__ float block_red_max(float v, volatile float* scr, int tid) {
#pragma unroll
  for (int o = 32; o >= 1; o >>= 1) v = fmaxf(v, __shfl_xor(v, o));
  if ((tid & 63) == 0) scr[tid >> 6] = v;
  __syncthreads();
  if (tid < 64) {
    float w = (tid < 16) ? scr[tid] : -3.0e38f;
#pragma unroll
    for (int o = 8; o >= 1; o >>= 1) w = fmaxf(w, __shfl_xor(w, o));
    if (tid == 0) scr[16] = w;
  }
  __syncthreads();
  return scr[16];
}
__device__ __forceinline__ float block_red_sum(float v, volatile float* scr, int tid) {
#pragma unroll
  for (int o = 32; o >= 1; o >>= 1) v += __shfl_xor(v, o);
  if ((tid & 63) == 0) scr[tid >> 6] = v;
  __syncthreads();
  if (tid < 64) {
    float w = (tid < 16) ? scr[tid] : 0.f;
#pragma unroll
    for (int o = 8; o >= 1; o >>= 1) w += __shfl_xor(w, o);
    if (tid == 0) scr[16] = w;
  }
  __syncthreads();
  return scr[16];
}

#define TPV(k, i) __uint_as_float(((i) & 1) ? (Tp[k][(i) >> 1] & 0xffff0000u) : (Tp[k][(i) >> 1] << 16))

__launch_bounds__(1024)
__global__ void k_forward(const float* __restrict__ em, const float* __restrict__ prior_w,
                          const unsigned short* __restrict__ Tt, float* __restrict__ out) {
  __shared__ float qbuf[2][16448];      // +32 guard on each side (valid interior at [32,16416))
  __shared__ float scr[20];
  const int tid = threadIdx.x;
  const int b = blockIdx.x;
  const int x = tid & 31, y = (tid >> 5) & 31;

  if (tid < 64) {                       // zero the guard cells (masked reads must give 0, not NaN)
    int g = (tid < 32) ? tid : (16416 + tid - 32);
    qbuf[0][g] = 0.f; qbuf[1][g] = 0.f;
  }

  // persist all 7 transition probs per owned state, packed bf16 pairs over z
  unsigned int Tp[7][8];
  const int offs[7] = {0, 1, -1, 32, -32, 1024, 2048};
#pragma unroll
  for (int k = 0; k < 7; ++k) {
#pragma unroll
    for (int ii = 0; ii < 8; ++ii) {
      unsigned int w = 0;
#pragma unroll
      for (int h = 0; h < 2; ++h) {
        const int i = ii * 2 + h;
        const int sidx = i * PLANE + tid;
        int prev = sidx - offs[k];
        prev = prev < 0 ? 0 : (prev > (S_TOT - 1) ? (S_TOT - 1) : prev);
        const bool valid = (k == 0)
          || (k == 1 && x > 0)  || (k == 2 && x < 31)
          || (k == 3 && y > 0)  || (k == 4 && y < 31)
          || (k == 5 && i >= 1) || (k == 6 && i >= 2);
        unsigned int tv = valid ? (unsigned int)Tt[(size_t)k * S_TOT + prev] : 0u;
        w |= tv << (16 * h);
      }
      Tp[k][ii] = w;
    }
  }

  // ---- t = 0: alpha0 = em0 + prior_w - prior_lse ----
  float pw[16], em_r[16];
#pragma unroll
  for (int i = 0; i < 16; ++i) pw[i] = prior_w[i * PLANE + tid];
  const float* em0 = em + (size_t)(b * T_T) * S_TOT;
#pragma unroll
  for (int i = 0; i < 16; ++i) em_r[i] = em0[i * PLANE + tid];

  float pm = pw[0];
#pragma unroll
  for (int i = 1; i < 16; ++i) pm = fmaxf(pm, pw[i]);
  const float Mp = block_red_max(pm, scr, tid);
  float pse = 0.f;
#pragma unroll
  for (int i = 0; i < 16; ++i) pse += expf(pw[i] - Mp);
  const float Sp = block_red_sum(pse, scr, tid);
  const float prior_lse = Mp + logf(Sp);

  float vm = em_r[0] + pw[0];
#pragma unroll
  for (int i = 1; i < 16; ++i) vm = fmaxf(vm, em_r[i] + pw[i]);
  const float M0 = block_red_max(vm, scr, tid);

  float qr[16]; float psum = 0.f;
#pragma unroll
  for (int i = 0; i < 16; ++i) {
    float u = __expf(em_r[i] + pw[i] - M0);
    qr[i] = u; psum += u;
    qbuf[0][32 + i * PLANE + tid] = u;
  }
  float Z = block_red_sum(psum, scr, tid);
  float logZ = logf(Z);
  float C = M0 - prior_lse + logZ;

  int cur = 0;
  for (int t = 1; t < T_T; ++t) {
    const float* emt = em + (size_t)(b * T_T + t) * S_TOT;
#pragma unroll
    for (int i = 0; i < 16; ++i) em_r[i] = emt[i * PLANE + tid];
    float mm = em_r[0];
#pragma unroll
    for (int i = 1; i < 16; ++i) mm = fmaxf(mm, em_r[i]);
    const float M = block_red_max(mm, scr, tid);
    const float shift = M + logZ;       // fold 1/Z_prev into the exp

    const float* qc = &qbuf[cur][32];
    float* qw = &qbuf[cur ^ 1][32];
    float qm1 = 0.f, qm2 = 0.f;         // old qr[i-1], qr[i-2] (z-1, z-2 from registers)
    float pps = 0.f;
#pragma unroll
    for (int i = 0; i < 16; ++i) {
      const int si = i * PLANE + tid;
      const float qold = qr[i];
      float sig = qold      * TPV(0, i)
                + qc[si - 1]  * TPV(1, i)
                + qc[si + 1]  * TPV(2, i)
                + qc[si - 32] * TPV(3, i)
                + qc[si + 32] * TPV(4, i)
                + qm1         * TPV(5, i)
                + qm2         * TPV(6, i);
      const float u = __expf(em_r[i] - shift) * sig;
      qr[i] = u; pps += u;
      qw[si] = u;
      qm2 = qm1; qm1 = qold;
    }
    const float Zt = block_red_sum(pps, scr, tid);  // barrier also publishes qw writes
    logZ = logf(Zt);
    C += M + logZ;
    cur ^= 1;
  }
  if (tid == 0) out[b] = C;
}

extern "C" void kernel_launch(void* const* d_in, const int* in_sizes, int n_in,
                              void* d_out, int out_size, void* d_ws, size_t ws_size,
                              hipStream_t stream) {
  (void)in_sizes; (void)n_in; (void)out_size; (void)ws_size;
  const int*   stories      = (const int*)d_in[0];
  const float* emission_w   = (const float*)d_in[3];
  const float* transition_w = (const float*)d_in[4];
  const float* prior_w      = (const float*)d_in[5];
  float* out = (float*)d_out;
  char* ws = (char*)d_ws;
  unsigned short* Et = (unsigned short*)(ws + OFF_ET);
  float*          em = (float*)(ws + OFF_EM);
  float*         lse = (float*)(ws + OFF_LSE);
  unsigned short* Tt = (unsigned short*)(ws + OFF_TT);

  hipLaunchKernelGGL(k_row_lse,   dim3(S_TOT),   dim3(128), 0, stream, emission_w, lse);
  hipLaunchKernelGGL(k_transpose, dim3(256, 64), dim3(256), 0, stream, emission_w, Et);
  hipLaunchKernelGGL(k_tsoftmax,  dim3(64),      dim3(256), 0, stream, transition_w, Tt);
  hipLaunchKernelGGL(k_em,        dim3(8, 2048), dim3(256), 0, stream, Et, stories, lse, em);
  hipLaunchKernelGGL(k_forward,   dim3(B_B),     dim3(1024), 0, stream, em, prior_w, Tt, out);
}